// Round 1
// baseline (8997.192 us; speedup 1.0000x reference)
//
#include <hip/hip_runtime.h>
#include <hip/hip_bf16.h>
#include <math.h>

#define N_NODES 10000
#define NE      640000
#define NTOT    (NE + N_NODES)   // edges + self loops
#define HC      1024             // H*C
#define CC      512              // per-head channels

// ---------- helpers: monotone f32<->u32 encoding for atomicMax ----------
__device__ __forceinline__ unsigned enc_f32(float f) {
    unsigned u = __float_as_uint(f);
    return (u & 0x80000000u) ? ~u : (u | 0x80000000u);
}
__device__ __forceinline__ float dec_f32(unsigned u) {
    return __uint_as_float((u & 0x80000000u) ? (u & 0x7FFFFFFFu) : ~u);
}
__device__ __forceinline__ float lrelu(float v) { return v >= 0.f ? v : 0.2f * v; }

// ---------- generic 64x64 tiled fp32 GEMM, optional fused ops ----------
// C[M,N] = act( A'[M,K] @ B[K,N] + biasC ),  A' = ACT_IN ? relu(A + biasA[k]) : A
template<int ACT_IN, int RELU_OUT>
__global__ __launch_bounds__(256) void gemm64(
    const float* __restrict__ A, const float* __restrict__ biasA,
    const float* __restrict__ B, const float* __restrict__ biasC,
    float* __restrict__ C, int M, int N, int K)
{
    __shared__ float As[16][68];
    __shared__ float Bs[16][68];
    const int bm = blockIdx.y * 64;
    const int bn = blockIdx.x * 64;
    const int tid = threadIdx.x;
    const int tx = tid & 15, ty = tid >> 4;

    const int arow  = tid >> 2;        // 0..63
    const int acol4 = (tid & 3) * 4;   // 0,4,8,12
    const int brow  = tid >> 4;        // 0..15
    const int bcol4 = (tid & 15) * 4;  // 0..60

    float acc[4][4] = {};

    for (int k0 = 0; k0 < K; k0 += 16) {
        // A tile (64 rows x 16 k), stored transposed As[k][m]
        int gr = bm + arow;
        float4 av = make_float4(0.f, 0.f, 0.f, 0.f);
        if (gr < M) av = *(const float4*)(A + (size_t)gr * K + k0 + acol4);
        if (ACT_IN) {
            av.x = fmaxf(av.x + biasA[k0 + acol4 + 0], 0.f);
            av.y = fmaxf(av.y + biasA[k0 + acol4 + 1], 0.f);
            av.z = fmaxf(av.z + biasA[k0 + acol4 + 2], 0.f);
            av.w = fmaxf(av.w + biasA[k0 + acol4 + 3], 0.f);
        }
        As[acol4 + 0][arow] = av.x;
        As[acol4 + 1][arow] = av.y;
        As[acol4 + 2][arow] = av.z;
        As[acol4 + 3][arow] = av.w;
        // B tile (16 k x 64 cols)
        float4 bv = *(const float4*)(B + (size_t)(k0 + brow) * N + bn + bcol4);
        *(float4*)&Bs[brow][bcol4] = bv;
        __syncthreads();
        #pragma unroll
        for (int k = 0; k < 16; ++k) {
            float a0 = As[k][ty * 4 + 0], a1 = As[k][ty * 4 + 1];
            float a2 = As[k][ty * 4 + 2], a3 = As[k][ty * 4 + 3];
            float b0 = Bs[k][tx * 4 + 0], b1 = Bs[k][tx * 4 + 1];
            float b2 = Bs[k][tx * 4 + 2], b3 = Bs[k][tx * 4 + 3];
            acc[0][0] += a0 * b0; acc[0][1] += a0 * b1; acc[0][2] += a0 * b2; acc[0][3] += a0 * b3;
            acc[1][0] += a1 * b0; acc[1][1] += a1 * b1; acc[1][2] += a1 * b2; acc[1][3] += a1 * b3;
            acc[2][0] += a2 * b0; acc[2][1] += a2 * b1; acc[2][2] += a2 * b2; acc[2][3] += a2 * b3;
            acc[3][0] += a3 * b0; acc[3][1] += a3 * b1; acc[3][2] += a3 * b2; acc[3][3] += a3 * b3;
        }
        __syncthreads();
    }
    #pragma unroll
    for (int i = 0; i < 4; ++i) {
        int row = bm + ty * 4 + i;
        if (row >= M) continue;
        #pragma unroll
        for (int j = 0; j < 4; ++j) {
            int col = bn + tx * 4 + j;
            float v = acc[i][j];
            if (biasC) v += biasC[col];
            if (RELU_OUT) v = fmaxf(v, 0.f);
            C[(size_t)row * N + col] = v;
        }
    }
}

// ---------- attention dot products: a_src/a_dst [N*H] ----------
__global__ __launch_bounds__(256) void att_dots(
    const float* __restrict__ h, const float* __restrict__ att_src,
    const float* __restrict__ att_dst, float* __restrict__ a_src,
    float* __restrict__ a_dst)
{
    int wave = threadIdx.x >> 6;
    int lane = threadIdx.x & 63;
    int p = blockIdx.x * 4 + wave;      // (node, head) pair index
    if (p >= N_NODES * 2) return;
    int n = p >> 1, hd = p & 1;
    const float* hp = h + (size_t)n * HC + hd * CC;
    const float* as = att_src + hd * CC;
    const float* ad = att_dst + hd * CC;
    float s1 = 0.f, s2 = 0.f;
    for (int c = lane; c < CC; c += 64) {
        float hv = hp[c];
        s1 += hv * as[c];
        s2 += hv * ad[c];
    }
    #pragma unroll
    for (int o = 32; o > 0; o >>= 1) {
        s1 += __shfl_xor(s1, o);
        s2 += __shfl_xor(s2, o);
    }
    if (lane == 0) { a_src[p] = s1; a_dst[p] = s2; }
}

// ---------- segment max over dst ----------
__global__ __launch_bounds__(256) void edge_max(
    const int* __restrict__ ei, const float* __restrict__ a_src,
    const float* __restrict__ a_dst, unsigned* __restrict__ m_enc)
{
    int e = blockIdx.x * blockDim.x + threadIdx.x;
    if (e >= NTOT) return;
    int s, d;
    if (e < NE) { s = ei[e]; d = ei[NE + e]; } else { s = d = e - NE; }
    #pragma unroll
    for (int hd = 0; hd < 2; ++hd) {
        float v = lrelu(a_src[s * 2 + hd] + a_dst[d * 2 + hd]);
        atomicMax(&m_enc[d * 2 + hd], enc_f32(v));
    }
}

// ---------- segment sum of exp ----------
__global__ __launch_bounds__(256) void edge_sum(
    const int* __restrict__ ei, const float* __restrict__ a_src,
    const float* __restrict__ a_dst, const unsigned* __restrict__ m_enc,
    float* __restrict__ denom)
{
    int e = blockIdx.x * blockDim.x + threadIdx.x;
    if (e >= NTOT) return;
    int s, d;
    if (e < NE) { s = ei[e]; d = ei[NE + e]; } else { s = d = e - NE; }
    #pragma unroll
    for (int hd = 0; hd < 2; ++hd) {
        float v = lrelu(a_src[s * 2 + hd] + a_dst[d * 2 + hd]);
        float ex = expf(v - dec_f32(m_enc[d * 2 + hd]));
        atomicAdd(&denom[d * 2 + hd], ex);
    }
}

// ---------- weighted scatter-add aggregation (one block per edge) ----------
__global__ __launch_bounds__(256) void aggregate(
    const int* __restrict__ ei, const float* __restrict__ a_src,
    const float* __restrict__ a_dst, const unsigned* __restrict__ m_enc,
    const float* __restrict__ denom, const float* __restrict__ h,
    float* __restrict__ out_feat)
{
    int e = blockIdx.x;
    int s, d;
    if (e < NE) { s = ei[e]; d = ei[NE + e]; } else { s = d = e - NE; }
    int c4 = threadIdx.x * 4;           // 0..1020
    int hd = c4 >> 9;                   // head
    float v = lrelu(a_src[s * 2 + hd] + a_dst[d * 2 + hd]);
    float alpha = expf(v - dec_f32(m_enc[d * 2 + hd])) / denom[d * 2 + hd];
    float4 hv = *(const float4*)(h + (size_t)s * HC + c4);
    float* op = out_feat + (size_t)d * HC + c4;
    atomicAdd(op + 0, alpha * hv.x);
    atomicAdd(op + 1, alpha * hv.y);
    atomicAdd(op + 2, alpha * hv.z);
    atomicAdd(op + 3, alpha * hv.w);
}

// ---------- final tiny layer + squared norms ----------
__global__ __launch_bounds__(256) void mlp3_sq(
    const float* __restrict__ y3, const float* __restrict__ W3,
    const float* __restrict__ b3, float* __restrict__ y, float* __restrict__ sq)
{
    int n = blockIdx.x * blockDim.x + threadIdx.x;
    if (n >= N_NODES) return;
    float acc0 = b3[0], acc1 = b3[1], acc2 = b3[2];
    const float* r = y3 + (size_t)n * 64;
    #pragma unroll 8
    for (int k = 0; k < 64; ++k) {
        float v = r[k];
        acc0 += v * W3[k * 3 + 0];
        acc1 += v * W3[k * 3 + 1];
        acc2 += v * W3[k * 3 + 2];
    }
    y[n * 3 + 0] = acc0; y[n * 3 + 1] = acc1; y[n * 3 + 2] = acc2;
    sq[n] = acc0 * acc0 + acc1 * acc1 + acc2 * acc2;
}

// ---------- pairwise distances (gram trick, matches reference) ----------
__global__ __launch_bounds__(256) void pdist(
    const float* __restrict__ y, const float* __restrict__ sq,
    float* __restrict__ out)
{
    int i = blockIdx.y;
    int j0 = (blockIdx.x * 256 + threadIdx.x) * 4;
    if (j0 >= N_NODES) return;
    float yi0 = y[i * 3 + 0], yi1 = y[i * 3 + 1], yi2 = y[i * 3 + 2];
    float si = sq[i];
    float res[4];
    #pragma unroll
    for (int t = 0; t < 4; ++t) {
        int j = j0 + t;
        float d2 = si + sq[j] - 2.f * (yi0 * y[j * 3 + 0] + yi1 * y[j * 3 + 1] + yi2 * y[j * 3 + 2]);
        d2 = fmaxf(d2, 0.f);
        res[t] = d2 > 0.f ? sqrtf(d2) : 0.f;
    }
    *(float4*)(out + (size_t)i * N_NODES + j0) = make_float4(res[0], res[1], res[2], res[3]);
}

extern "C" void kernel_launch(void* const* d_in, const int* in_sizes, int n_in,
                              void* d_out, int out_size, void* d_ws, size_t ws_size,
                              hipStream_t stream) {
    const float* x         = (const float*)d_in[0];
    const int*   ei        = (const int*)d_in[1];
    const float* W         = (const float*)d_in[2];
    const float* att_src   = (const float*)d_in[3];
    const float* att_dst   = (const float*)d_in[4];
    const float* bias_conv = (const float*)d_in[5];
    const float* Wa        = (const float*)d_in[6];
    const float* ba        = (const float*)d_in[7];
    const float* W1        = (const float*)d_in[8];
    const float* b1        = (const float*)d_in[9];
    const float* W2        = (const float*)d_in[10];
    const float* b2        = (const float*)d_in[11];
    const float* W3        = (const float*)d_in[12];
    const float* b3        = (const float*)d_in[13];
    float* out = (float*)d_out;

    // big intermediates live in the (huge) d_out and are overwritten at the end
    float* h        = out;                 // [10000,1024]
    float* out_feat = out + 10240000;      // [10000,1024]
    float* y1       = out + 20480000;      // [10000,256]
    float* y2       = out + 23040000;      // [10000,128]
    float* y3       = out + 24320000;      // [10000,64]

    // survivors of the final overwrite go in ws
    float*    ws_f   = (float*)d_ws;
    float*    a_src  = ws_f;                      // 20000
    float*    a_dst  = ws_f + 20000;              // 20000
    unsigned* m_enc  = (unsigned*)(ws_f + 40000); // 20000
    float*    denom  = ws_f + 60000;              // 20000
    float*    y      = ws_f + 80000;              // 30000
    float*    sq     = ws_f + 110000;             // 10000

    hipMemsetAsync(out_feat, 0, (size_t)10240000 * sizeof(float), stream);
    hipMemsetAsync(m_enc, 0, 20000 * sizeof(unsigned), stream);
    hipMemsetAsync(denom, 0, 20000 * sizeof(float), stream);

    // h = x @ W
    gemm64<0, 0><<<dim3(1024 / 64, (N_NODES + 63) / 64), 256, 0, stream>>>(
        x, nullptr, W, nullptr, h, N_NODES, 1024, 512);

    att_dots<<<(N_NODES * 2 + 3) / 4, 256, 0, stream>>>(h, att_src, att_dst, a_src, a_dst);

    edge_max<<<(NTOT + 255) / 256, 256, 0, stream>>>(ei, a_src, a_dst, m_enc);
    edge_sum<<<(NTOT + 255) / 256, 256, 0, stream>>>(ei, a_src, a_dst, m_enc, denom);
    aggregate<<<NTOT, 256, 0, stream>>>(ei, a_src, a_dst, m_enc, denom, h, out_feat);

    // MLP
    gemm64<1, 1><<<dim3(256 / 64, (N_NODES + 63) / 64), 256, 0, stream>>>(
        out_feat, bias_conv, Wa, ba, y1, N_NODES, 256, 1024);
    gemm64<0, 1><<<dim3(128 / 64, (N_NODES + 63) / 64), 256, 0, stream>>>(
        y1, nullptr, W1, b1, y2, N_NODES, 128, 256);
    gemm64<0, 1><<<dim3(64 / 64, (N_NODES + 63) / 64), 256, 0, stream>>>(
        y2, nullptr, W2, b2, y3, N_NODES, 64, 128);
    mlp3_sq<<<(N_NODES + 255) / 256, 256, 0, stream>>>(y3, W3, b3, y, sq);

    // final N x N distance matrix overwrites all of d_out
    pdist<<<dim3((N_NODES + 1023) / 1024, N_NODES), 256, 0, stream>>>(y, sq, out);
}

// Round 2
// 838.911 us; speedup vs baseline: 10.7249x; 10.7249x over previous
//
#include <hip/hip_runtime.h>
#include <hip/hip_bf16.h>
#include <math.h>

#define N_NODES 10000
#define NE      640000
#define NTOT    (NE + N_NODES)   // edges + self loops
#define HC      1024             // H*C
#define CC      512              // per-head channels

__device__ __forceinline__ float lrelu(float v) { return v >= 0.f ? v : 0.2f * v; }

// ---------- generic 64x64 tiled fp32 GEMM, optional fused ops ----------
// C[M,N] = act( A'[M,K] @ B[K,N] + biasC ),  A' = ACT_IN ? relu(A + biasA[k]) : A
template<int ACT_IN, int RELU_OUT>
__global__ __launch_bounds__(256) void gemm64(
    const float* __restrict__ A, const float* __restrict__ biasA,
    const float* __restrict__ B, const float* __restrict__ biasC,
    float* __restrict__ C, int M, int N, int K)
{
    __shared__ float As[16][68];
    __shared__ float Bs[16][68];
    const int bm = blockIdx.y * 64;
    const int bn = blockIdx.x * 64;
    const int tid = threadIdx.x;
    const int tx = tid & 15, ty = tid >> 4;

    const int arow  = tid >> 2;        // 0..63
    const int acol4 = (tid & 3) * 4;   // 0,4,8,12
    const int brow  = tid >> 4;        // 0..15
    const int bcol4 = (tid & 15) * 4;  // 0..60

    float acc[4][4] = {};

    for (int k0 = 0; k0 < K; k0 += 16) {
        int gr = bm + arow;
        float4 av = make_float4(0.f, 0.f, 0.f, 0.f);
        if (gr < M) av = *(const float4*)(A + (size_t)gr * K + k0 + acol4);
        if (ACT_IN) {
            av.x = fmaxf(av.x + biasA[k0 + acol4 + 0], 0.f);
            av.y = fmaxf(av.y + biasA[k0 + acol4 + 1], 0.f);
            av.z = fmaxf(av.z + biasA[k0 + acol4 + 2], 0.f);
            av.w = fmaxf(av.w + biasA[k0 + acol4 + 3], 0.f);
        }
        As[acol4 + 0][arow] = av.x;
        As[acol4 + 1][arow] = av.y;
        As[acol4 + 2][arow] = av.z;
        As[acol4 + 3][arow] = av.w;
        float4 bv = *(const float4*)(B + (size_t)(k0 + brow) * N + bn + bcol4);
        *(float4*)&Bs[brow][bcol4] = bv;
        __syncthreads();
        #pragma unroll
        for (int k = 0; k < 16; ++k) {
            float a0 = As[k][ty * 4 + 0], a1 = As[k][ty * 4 + 1];
            float a2 = As[k][ty * 4 + 2], a3 = As[k][ty * 4 + 3];
            float b0 = Bs[k][tx * 4 + 0], b1 = Bs[k][tx * 4 + 1];
            float b2 = Bs[k][tx * 4 + 2], b3 = Bs[k][tx * 4 + 3];
            acc[0][0] += a0 * b0; acc[0][1] += a0 * b1; acc[0][2] += a0 * b2; acc[0][3] += a0 * b3;
            acc[1][0] += a1 * b0; acc[1][1] += a1 * b1; acc[1][2] += a1 * b2; acc[1][3] += a1 * b3;
            acc[2][0] += a2 * b0; acc[2][1] += a2 * b1; acc[2][2] += a2 * b2; acc[2][3] += a2 * b3;
            acc[3][0] += a3 * b0; acc[3][1] += a3 * b1; acc[3][2] += a3 * b2; acc[3][3] += a3 * b3;
        }
        __syncthreads();
    }
    #pragma unroll
    for (int i = 0; i < 4; ++i) {
        int row = bm + ty * 4 + i;
        if (row >= M) continue;
        #pragma unroll
        for (int j = 0; j < 4; ++j) {
            int col = bn + tx * 4 + j;
            float v = acc[i][j];
            if (biasC) v += biasC[col];
            if (RELU_OUT) v = fmaxf(v, 0.f);
            C[(size_t)row * N + col] = v;
        }
    }
}

// ---------- attention dot products: a_src/a_dst [N*H] ----------
__global__ __launch_bounds__(256) void att_dots(
    const float* __restrict__ h, const float* __restrict__ att_src,
    const float* __restrict__ att_dst, float* __restrict__ a_src,
    float* __restrict__ a_dst)
{
    int wave = threadIdx.x >> 6;
    int lane = threadIdx.x & 63;
    int p = blockIdx.x * 4 + wave;      // (node, head) pair index
    if (p >= N_NODES * 2) return;
    int n = p >> 1, hd = p & 1;
    const float* hp = h + (size_t)n * HC + hd * CC;
    const float* as = att_src + hd * CC;
    const float* ad = att_dst + hd * CC;
    float s1 = 0.f, s2 = 0.f;
    for (int c = lane; c < CC; c += 64) {
        float hv = hp[c];
        s1 += hv * as[c];
        s2 += hv * ad[c];
    }
    #pragma unroll
    for (int o = 32; o > 0; o >>= 1) {
        s1 += __shfl_xor(s1, o);
        s2 += __shfl_xor(s2, o);
    }
    if (lane == 0) { a_src[p] = s1; a_dst[p] = s2; }
}

// ---------- CSR build ----------
__global__ __launch_bounds__(256) void count_deg(
    const int* __restrict__ ei, int* __restrict__ deg)
{
    int e = blockIdx.x * blockDim.x + threadIdx.x;
    if (e >= NTOT) return;
    int d = (e < NE) ? ei[NE + e] : e - NE;
    atomicAdd(&deg[d], 1);
}

// one block of 1024 threads scans 10240 degrees -> exclusive row_start[10001]
__global__ __launch_bounds__(1024) void scan_deg(
    const int* __restrict__ deg, int* __restrict__ row_start)
{
    __shared__ int part[1024];
    int t = threadIdx.x;
    int base = t * 10;
    int local[10];
    int s = 0;
    #pragma unroll
    for (int j = 0; j < 10; ++j) { local[j] = deg[base + j]; s += local[j]; }
    part[t] = s;
    __syncthreads();
    for (int off = 1; off < 1024; off <<= 1) {
        int v = (t >= off) ? part[t - off] : 0;
        __syncthreads();
        part[t] += v;
        __syncthreads();
    }
    int run = (t == 0) ? 0 : part[t - 1];   // exclusive prefix
    #pragma unroll
    for (int j = 0; j < 10; ++j) {
        if (base + j <= N_NODES) row_start[base + j] = run;
        run += local[j];
    }
}

__global__ __launch_bounds__(256) void scatter_edges(
    const int* __restrict__ ei, const int* __restrict__ row_start,
    int* __restrict__ cursor, int* __restrict__ srclist)
{
    int e = blockIdx.x * blockDim.x + threadIdx.x;
    if (e >= NTOT) return;
    int s, d;
    if (e < NE) { s = ei[e]; d = ei[NE + e]; } else { s = d = e - NE; }
    int pos = atomicAdd(&cursor[d], 1);
    srclist[row_start[d] + pos] = s;
}

// ---------- per-dst softmax stats (max + denom), one wave per dst ----------
__global__ __launch_bounds__(256) void seg_softmax_stats(
    const int* __restrict__ row_start, const int* __restrict__ srclist,
    const float* __restrict__ a_src, const float* __restrict__ a_dst,
    float* __restrict__ m, float* __restrict__ denom)
{
    int wave = threadIdx.x >> 6;
    int lane = threadIdx.x & 63;
    int d = blockIdx.x * 4 + wave;
    if (d >= N_NODES) return;
    int beg = row_start[d], end = row_start[d + 1];
    float ad0 = a_dst[d * 2], ad1 = a_dst[d * 2 + 1];
    float m0 = -INFINITY, m1 = -INFINITY;
    for (int i = beg + lane; i < end; i += 64) {
        int s = srclist[i];
        m0 = fmaxf(m0, lrelu(a_src[s * 2 + 0] + ad0));
        m1 = fmaxf(m1, lrelu(a_src[s * 2 + 1] + ad1));
    }
    #pragma unroll
    for (int o = 32; o > 0; o >>= 1) {
        m0 = fmaxf(m0, __shfl_xor(m0, o));
        m1 = fmaxf(m1, __shfl_xor(m1, o));
    }
    float s0 = 0.f, s1 = 0.f;
    for (int i = beg + lane; i < end; i += 64) {
        int s = srclist[i];
        s0 += expf(lrelu(a_src[s * 2 + 0] + ad0) - m0);
        s1 += expf(lrelu(a_src[s * 2 + 1] + ad1) - m1);
    }
    #pragma unroll
    for (int o = 32; o > 0; o >>= 1) {
        s0 += __shfl_xor(s0, o);
        s1 += __shfl_xor(s1, o);
    }
    if (lane == 0) {
        m[d * 2 + 0] = m0; m[d * 2 + 1] = m1;
        denom[d * 2 + 0] = s0; denom[d * 2 + 1] = s1;
    }
}

// ---------- gather aggregation: one block per dst, no atomics ----------
__global__ __launch_bounds__(256) void aggregate_csr(
    const int* __restrict__ row_start, const int* __restrict__ srclist,
    const float* __restrict__ a_src, const float* __restrict__ a_dst,
    const float* __restrict__ m, const float* __restrict__ denom,
    const float* __restrict__ h, float* __restrict__ out_feat)
{
    __shared__ int   sS[256];
    __shared__ float sA0[256];
    __shared__ float sA1[256];
    int d = blockIdx.x;
    int tid = threadIdx.x;
    int beg = row_start[d], end = row_start[d + 1];
    float ad0 = a_dst[d * 2], ad1 = a_dst[d * 2 + 1];
    float m0 = m[d * 2], m1 = m[d * 2 + 1];
    float inv0 = 1.f / denom[d * 2], inv1 = 1.f / denom[d * 2 + 1];
    int c4 = tid * 4;                   // channel quad owned by this thread
    int hd = tid >> 7;                  // head (wave-uniform)
    float4 acc = make_float4(0.f, 0.f, 0.f, 0.f);

    for (int base = beg; base < end; base += 256) {
        int i = base + tid;
        if (i < end) {
            int s = srclist[i];
            sS[tid] = s;
            sA0[tid] = expf(lrelu(a_src[s * 2 + 0] + ad0) - m0) * inv0;
            sA1[tid] = expf(lrelu(a_src[s * 2 + 1] + ad1) - m1) * inv1;
        }
        __syncthreads();
        int cnt = min(256, end - base);
        for (int j = 0; j < cnt; ++j) {
            int s = sS[j];
            float al = (hd == 0) ? sA0[j] : sA1[j];
            float4 hv = *(const float4*)(h + (size_t)s * HC + c4);
            acc.x += al * hv.x; acc.y += al * hv.y;
            acc.z += al * hv.z; acc.w += al * hv.w;
        }
        __syncthreads();
    }
    *(float4*)(out_feat + (size_t)d * HC + c4) = acc;
}

// ---------- final tiny layer + squared norms ----------
__global__ __launch_bounds__(256) void mlp3_sq(
    const float* __restrict__ y3, const float* __restrict__ W3,
    const float* __restrict__ b3, float* __restrict__ y, float* __restrict__ sq)
{
    int n = blockIdx.x * blockDim.x + threadIdx.x;
    if (n >= N_NODES) return;
    float acc0 = b3[0], acc1 = b3[1], acc2 = b3[2];
    const float* r = y3 + (size_t)n * 64;
    #pragma unroll 8
    for (int k = 0; k < 64; ++k) {
        float v = r[k];
        acc0 += v * W3[k * 3 + 0];
        acc1 += v * W3[k * 3 + 1];
        acc2 += v * W3[k * 3 + 2];
    }
    y[n * 3 + 0] = acc0; y[n * 3 + 1] = acc1; y[n * 3 + 2] = acc2;
    sq[n] = acc0 * acc0 + acc1 * acc1 + acc2 * acc2;
}

// ---------- pairwise distances (gram trick, matches reference) ----------
__global__ __launch_bounds__(256) void pdist(
    const float* __restrict__ y, const float* __restrict__ sq,
    float* __restrict__ out)
{
    int i = blockIdx.y;
    int j0 = (blockIdx.x * 256 + threadIdx.x) * 4;
    if (j0 >= N_NODES) return;
    float yi0 = y[i * 3 + 0], yi1 = y[i * 3 + 1], yi2 = y[i * 3 + 2];
    float si = sq[i];
    float res[4];
    #pragma unroll
    for (int t = 0; t < 4; ++t) {
        int j = j0 + t;
        float d2 = si + sq[j] - 2.f * (yi0 * y[j * 3 + 0] + yi1 * y[j * 3 + 1] + yi2 * y[j * 3 + 2]);
        d2 = fmaxf(d2, 0.f);
        res[t] = d2 > 0.f ? sqrtf(d2) : 0.f;
    }
    *(float4*)(out + (size_t)i * N_NODES + j0) = make_float4(res[0], res[1], res[2], res[3]);
}

extern "C" void kernel_launch(void* const* d_in, const int* in_sizes, int n_in,
                              void* d_out, int out_size, void* d_ws, size_t ws_size,
                              hipStream_t stream) {
    const float* x         = (const float*)d_in[0];
    const int*   ei        = (const int*)d_in[1];
    const float* W         = (const float*)d_in[2];
    const float* att_src   = (const float*)d_in[3];
    const float* att_dst   = (const float*)d_in[4];
    const float* bias_conv = (const float*)d_in[5];
    const float* Wa        = (const float*)d_in[6];
    const float* ba        = (const float*)d_in[7];
    const float* W1        = (const float*)d_in[8];
    const float* b1        = (const float*)d_in[9];
    const float* W2        = (const float*)d_in[10];
    const float* b2        = (const float*)d_in[11];
    const float* W3        = (const float*)d_in[12];
    const float* b3        = (const float*)d_in[13];
    float* out = (float*)d_out;

    // all pre-pdist intermediates live in d_out (dead before pdist overwrites)
    float* h        = out;                 // [10000,1024]
    float* out_feat = out + 10240000;      // [10000,1024]
    float* y1       = out + 20480000;      // [10000,256]
    float* y2       = out + 23040000;      // [10000,128]
    float* y3       = out + 24320000;      // [10000,64]
    float* a_src    = out + 24960000;      // 20000
    float* a_dst    = out + 24980000;      // 20000
    float* mbuf     = out + 25000000;      // 20000
    float* denom    = out + 25020000;      // 20000
    int*   deg      = (int*)(out + 25040000); // 10240
    int*   row_st   = (int*)(out + 25060000); // 10001
    int*   cursor   = (int*)(out + 25080000); // 10240
    int*   srclist  = (int*)(out + 25100000); // 650000

    // survivors of the final overwrite go in ws
    float* y  = (float*)d_ws;             // 30000
    float* sq = (float*)d_ws + 30000;     // 10000

    hipMemsetAsync(deg, 0, 10240 * sizeof(int), stream);
    hipMemsetAsync(cursor, 0, 10240 * sizeof(int), stream);

    // h = x @ W
    gemm64<0, 0><<<dim3(1024 / 64, (N_NODES + 63) / 64), 256, 0, stream>>>(
        x, nullptr, W, nullptr, h, N_NODES, 1024, 512);

    att_dots<<<(N_NODES * 2 + 3) / 4, 256, 0, stream>>>(h, att_src, att_dst, a_src, a_dst);

    // CSR build
    count_deg<<<(NTOT + 255) / 256, 256, 0, stream>>>(ei, deg);
    scan_deg<<<1, 1024, 0, stream>>>(deg, row_st);
    scatter_edges<<<(NTOT + 255) / 256, 256, 0, stream>>>(ei, row_st, cursor, srclist);

    // softmax stats + gather aggregation (no float atomics anywhere)
    seg_softmax_stats<<<(N_NODES + 3) / 4, 256, 0, stream>>>(
        row_st, srclist, a_src, a_dst, mbuf, denom);
    aggregate_csr<<<N_NODES, 256, 0, stream>>>(
        row_st, srclist, a_src, a_dst, mbuf, denom, h, out_feat);

    // MLP
    gemm64<1, 1><<<dim3(256 / 64, (N_NODES + 63) / 64), 256, 0, stream>>>(
        out_feat, bias_conv, Wa, ba, y1, N_NODES, 256, 1024);
    gemm64<0, 1><<<dim3(128 / 64, (N_NODES + 63) / 64), 256, 0, stream>>>(
        y1, nullptr, W1, b1, y2, N_NODES, 128, 256);
    gemm64<0, 1><<<dim3(64 / 64, (N_NODES + 63) / 64), 256, 0, stream>>>(
        y2, nullptr, W2, b2, y3, N_NODES, 64, 128);
    mlp3_sq<<<(N_NODES + 255) / 256, 256, 0, stream>>>(y3, W3, b3, y, sq);

    // final N x N distance matrix overwrites all of d_out
    pdist<<<dim3((N_NODES + 1023) / 1024, N_NODES), 256, 0, stream>>>(y, sq, out);
}